// Round 5
// baseline (143.340 us; speedup 1.0000x reference)
//
#include <hip/hip_runtime.h>

// Row-wise dot product: out[n] = sum_d x[n][d] * y[n][d]
// N = 16384 rows, D = 1024 cols, fp32 in / fp32 out.
//
// R4: cross-row software pipeline. R0-R3 all delivered ~3.2-3.4 TB/s read.
// The untested structure: overlap each row-pair's serialized shuffle-reduce
// chain (~450 cyc of dependent ds-ops) with the NEXT pair's 16 in-flight
// loads. Two alternating register sets A/B, asm barriers pin issue order.
// Wave handles 8 rows = 4 pairs; 512 blocks x 4 waves; ~150 VGPRs expected.

#define D 1024

typedef float v4f __attribute__((ext_vector_type(4)));

__device__ __forceinline__ void load_pair(const float* __restrict__ x,
                                          const float* __restrict__ y,
                                          int row, int lane, v4f R[16]) {
    const v4f* __restrict__ x0 = (const v4f*)(x + (size_t)row * D);
    const v4f* __restrict__ y0 = (const v4f*)(y + (size_t)row * D);
    const v4f* __restrict__ x1 = (const v4f*)(x + (size_t)(row + 1) * D);
    const v4f* __restrict__ y1 = (const v4f*)(y + (size_t)(row + 1) * D);
    #pragma unroll
    for (int j = 0; j < 4; ++j) R[j]      = x0[lane + 64 * j];
    #pragma unroll
    for (int j = 0; j < 4; ++j) R[4 + j]  = y0[lane + 64 * j];
    #pragma unroll
    for (int j = 0; j < 4; ++j) R[8 + j]  = x1[lane + 64 * j];
    #pragma unroll
    for (int j = 0; j < 4; ++j) R[12 + j] = y1[lane + 64 * j];
}

__device__ __forceinline__ void reduce_store_pair(float* __restrict__ out,
                                                  int row, int lane,
                                                  const v4f R[16]) {
    float s0 = 0.0f, s1 = 0.0f;
    #pragma unroll
    for (int j = 0; j < 4; ++j) {
        s0 += R[j].x * R[4 + j].x + R[j].y * R[4 + j].y +
              R[j].z * R[4 + j].z + R[j].w * R[4 + j].w;
        s1 += R[8 + j].x * R[12 + j].x + R[8 + j].y * R[12 + j].y +
              R[8 + j].z * R[12 + j].z + R[8 + j].w * R[12 + j].w;
    }
    #pragma unroll
    for (int off = 32; off > 0; off >>= 1) {
        s0 += __shfl_down(s0, off, 64);
        s1 += __shfl_down(s1, off, 64);
    }
    if (lane == 0) {
        *(float2*)(out + row) = make_float2(s0, s1);
    }
}

#define PIN() asm volatile("" ::: "memory")

__global__ __launch_bounds__(256) void rowdot_kernel(const float* __restrict__ x,
                                                     const float* __restrict__ y,
                                                     float* __restrict__ out) {
    const int wave = threadIdx.x >> 6;
    const int lane = threadIdx.x & 63;
    const int w = blockIdx.x * 4 + wave;  // global wave id, 0..2047
    const int r = w * 8;                  // 8 rows per wave, 4 pairs

    v4f A[16], B[16];

    // software pipeline: loads(p+1) issued before reduce(p)
    load_pair(x, y, r + 0, lane, A);
    load_pair(x, y, r + 2, lane, B);
    PIN();
    reduce_store_pair(out, r + 0, lane, A);
    load_pair(x, y, r + 4, lane, A);
    PIN();
    reduce_store_pair(out, r + 2, lane, B);
    load_pair(x, y, r + 6, lane, B);
    PIN();
    reduce_store_pair(out, r + 4, lane, A);
    PIN();
    reduce_store_pair(out, r + 6, lane, B);
}

extern "C" void kernel_launch(void* const* d_in, const int* in_sizes, int n_in,
                              void* d_out, int out_size, void* d_ws, size_t ws_size,
                              hipStream_t stream) {
    const float* x = (const float*)d_in[0];
    const float* y = (const float*)d_in[1];
    float* out = (float*)d_out;
    const int N = out_size;  // 16384 rows

    // 8 rows/wave * 4 waves/block = 32 rows/block -> 512 blocks (2/CU)
    rowdot_kernel<<<N / 32, 256, 0, stream>>>(x, y, out);
}

// Round 6
// 139.919 us; speedup vs baseline: 1.0245x; 1.0245x over previous
//
#include <hip/hip_runtime.h>

// Row-wise dot product: out[n] = sum_d x[n][d] * y[n][d]
// N = 16384 rows, D = 1024 cols, fp32 in / fp32 out.
//
// R5: max TLP + forced clustering. Evidence R0-R4: delivered read BW pinned
// at 3.1-3.45 TB/s across all structures; best was R3 (8192 waves, 16 pinned
// loads); R4 (2048 waves, deep pipeline) regressed -> wave-level parallelism,
// not per-wave depth, sustains outstanding misses. This round: 1 row/wave,
// 8 pinned loads/wave (32 payload VGPRs -> ~56 total -> 8 waves/SIMD, full
// occupancy), 16384 waves. Plain temporal loads (L2/L3-resident halves hit).
// If this doesn't beat ~39us, the read path is saturated = roofline.

#define D 1024

typedef float v4f __attribute__((ext_vector_type(4)));

__global__ __launch_bounds__(256) void rowdot_kernel(const float* __restrict__ x,
                                                     const float* __restrict__ y,
                                                     float* __restrict__ out) {
    const int wave = threadIdx.x >> 6;
    const int lane = threadIdx.x & 63;
    const int row = blockIdx.x * 4 + wave;  // one row per wave

    const v4f* __restrict__ xr = (const v4f*)(x + (size_t)row * D);
    const v4f* __restrict__ yr = (const v4f*)(y + (size_t)row * D);

    // 8 independent 16B loads, pinned before any use.
    v4f a0 = xr[lane];
    v4f a1 = xr[lane + 64];
    v4f a2 = xr[lane + 128];
    v4f a3 = xr[lane + 192];
    v4f b0 = yr[lane];
    v4f b1 = yr[lane + 64];
    v4f b2 = yr[lane + 128];
    v4f b3 = yr[lane + 192];
    asm volatile("" ::: "memory");

    float s0 = a0.x * b0.x + a0.y * b0.y + a0.z * b0.z + a0.w * b0.w;
    float s1 = a1.x * b1.x + a1.y * b1.y + a1.z * b1.z + a1.w * b1.w;
    float s2 = a2.x * b2.x + a2.y * b2.y + a2.z * b2.z + a2.w * b2.w;
    float s3 = a3.x * b3.x + a3.y * b3.y + a3.z * b3.z + a3.w * b3.w;
    float v = (s0 + s1) + (s2 + s3);

    #pragma unroll
    for (int off = 32; off > 0; off >>= 1) {
        v += __shfl_down(v, off, 64);
    }

    if (lane == 0) {
        out[row] = v;
    }
}

extern "C" void kernel_launch(void* const* d_in, const int* in_sizes, int n_in,
                              void* d_out, int out_size, void* d_ws, size_t ws_size,
                              hipStream_t stream) {
    const float* x = (const float*)d_in[0];
    const float* y = (const float*)d_in[1];
    float* out = (float*)d_out;
    const int N = out_size;  // 16384 rows

    // 1 row/wave, 4 waves/block -> 4096 blocks
    rowdot_kernel<<<N / 4, 256, 0, stream>>>(x, y, out);
}

// Round 7
// 139.628 us; speedup vs baseline: 1.0266x; 1.0021x over previous
//
#include <hip/hip_runtime.h>

// Row-wise dot product: out[n] = sum_d x[n][d] * y[n][d]
// N = 16384 rows, D = 1024 cols, fp32 in / fp32 out.
//
// R6: hybrid read paths. All prior rounds pinned at ~3.3 TB/s delivered
// read BW regardless of structure -> hypothesis: per-CU outstanding-line
// (L1/MSHR) cap on the vector-load read path (~5.5 B/cyc/CU). Writes
// (fill: 6.5 TB/s) are posted and don't hit it. Test: route HALF the
// traffic (x) through the global_load_lds DMA engine (fire-and-forget,
// vmcnt-queued, no VGPR return -> possibly separate outstanding-request
// budget) while y uses normal vector loads. If paths are independent,
// they sum -> ~26-31 us. If neutral, ~3.3 TB/s is the read-path roofline.

#define D 1024

typedef float v4f __attribute__((ext_vector_type(4)));

typedef __attribute__((address_space(1))) const void g_void;
typedef __attribute__((address_space(3))) void l_void;

__global__ __launch_bounds__(256) void rowdot_kernel(const float* __restrict__ x,
                                                     const float* __restrict__ y,
                                                     float* __restrict__ out) {
    __shared__ float xbuf[4][D];  // 16 KB: one staged x-row per wave

    const int wave = threadIdx.x >> 6;
    const int lane = threadIdx.x & 63;
    const int row = blockIdx.x * 4 + wave;  // one row per wave

    const float* __restrict__ xr = x + (size_t)row * D;
    const v4f* __restrict__ yr = (const v4f*)(y + (size_t)row * D);

    // 4 async 1KB DMAs: global x-row -> LDS. Per instruction: lane i's 16B
    // go to (uniform LDS base) + 16*i. Fire-and-forget, tracked by vmcnt.
    #pragma unroll
    for (int j = 0; j < 4; ++j) {
        __builtin_amdgcn_global_load_lds(
            (g_void*)(xr + j * 256 + lane * 4),
            (l_void*)(&xbuf[wave][j * 256]),
            16, 0, 0);
    }

    // 4 normal vector loads of y into registers, concurrent with the DMAs.
    v4f b0 = yr[lane];
    v4f b1 = yr[lane + 64];
    v4f b2 = yr[lane + 128];
    v4f b3 = yr[lane + 192];

    // Drain all outstanding memory ops (DMA completions + y loads).
    __builtin_amdgcn_s_waitcnt(0);
    asm volatile("" ::: "memory");

    // Read staged x back from LDS (conflict-free contiguous float4).
    const v4f* xb = (const v4f*)&xbuf[wave][0];
    v4f a0 = xb[lane];
    v4f a1 = xb[lane + 64];
    v4f a2 = xb[lane + 128];
    v4f a3 = xb[lane + 192];

    float s0 = a0.x * b0.x + a0.y * b0.y + a0.z * b0.z + a0.w * b0.w;
    float s1 = a1.x * b1.x + a1.y * b1.y + a1.z * b1.z + a1.w * b1.w;
    float s2 = a2.x * b2.x + a2.y * b2.y + a2.z * b2.z + a2.w * b2.w;
    float s3 = a3.x * b3.x + a3.y * b3.y + a3.z * b3.z + a3.w * b3.w;
    float v = (s0 + s1) + (s2 + s3);

    #pragma unroll
    for (int off = 32; off > 0; off >>= 1) {
        v += __shfl_down(v, off, 64);
    }

    if (lane == 0) {
        out[row] = v;
    }
}

extern "C" void kernel_launch(void* const* d_in, const int* in_sizes, int n_in,
                              void* d_out, int out_size, void* d_ws, size_t ws_size,
                              hipStream_t stream) {
    const float* x = (const float*)d_in[0];
    const float* y = (const float*)d_in[1];
    float* out = (float*)d_out;
    const int N = out_size;  // 16384 rows

    // 1 row/wave, 4 waves/block -> 4096 blocks
    rowdot_kernel<<<N / 4, 256, 0, stream>>>(x, y, out);
}